// Round 2
// baseline (614.106 us; speedup 1.0000x reference)
//
#include <hip/hip_runtime.h>

// ---------------------------------------------------------------------------
// InterpretableMultiHeadAttention on MI355X (gfx950)
// B=8, S=1024, D=512, H=8, d_k=64
// Outputs (concat in d_out): out [B,S,D] fp32, attn [H,B,S,S] fp32 (256 MB)
//
// Round 2: decomposed pipeline of simple streaming kernels.
//   gemm_proj(mode0) x2 : qh, kh  bf16 [b][h][s][64]   (qh pre-scaled 1/8)
//   gemm_proj(mode2)    : vt      bf16 [b][64][1024]   (LDS-transposed store)
//   attn_scores         : exp(QK^T) bf16 slab [bh][s][s] + rinv = 1/rowsum
//   attn_pv             : attn = exp*rinv (fp32, coalesced) + PV MFMA
//                         -> head_bf [b][s][h*64+e] (mean folded via *0.125)
//   gemm_out            : out = head_bf @ Wo_replicated^T  (K=512)
// No atomics, no memset, no in-barrier-loop score recompute.
// ---------------------------------------------------------------------------

using short8 = __attribute__((ext_vector_type(8))) short;   // 8 x bf16
using f32x4  = __attribute__((ext_vector_type(4))) float;

static __device__ __forceinline__ short f2bf(float f) {
    union { float f; unsigned u; } x; x.f = f;
    unsigned r = x.u + 0x7fffu + ((x.u >> 16) & 1u);
    return (short)(r >> 16);
}
static __device__ __forceinline__ float bfhi2f(unsigned hi_bits) {
    union { unsigned u; float f; } x; x.u = hi_bits;
    return x.f;
}

// ---------------------------------------------------------------------------
// 128x128-tile bf16 MFMA GEMM: C[m][n] = sum_k A[m][k] * W[n][k]
// A fp32 [8192][K]; W fp32 [N][K].
// mode 0: bf16 out [b][h][s][e]  (b=m>>10, s=m&1023, h=n>>6, e=n&63)
// mode 2: bf16 out [b][e][s]     (n<64; LDS-transposed coalesced store)
// ---------------------------------------------------------------------------
__global__ __launch_bounds__(256) void gemm_proj(
    const float* __restrict__ A, const float* __restrict__ W,
    short* __restrict__ out, int N, int K, float scale, int mode)
{
    __shared__ short smem[10240];              // 20 KB
    short (*As)[40] = (short(*)[40])smem;      // 128 x 32 (+8 pad)
    short (*Bs)[40] = (short(*)[40])(smem + 5120);
    short (*ts)[136] = (short(*)[136])smem;    // mode-2 transpose buffer (alias)

    const int tid  = threadIdx.x;
    const int m0   = blockIdx.x * 128;
    const int n0   = blockIdx.y * 128;
    const int lane = tid & 63, wave = tid >> 6;
    const int wm   = (wave & 1) * 64, wn = (wave >> 1) * 64;
    const int lrow = lane & 15, lq = lane >> 4;

    f32x4 acc[4][4] = {};

    for (int k0 = 0; k0 < K; k0 += 32) {
#pragma unroll
        for (int i = 0; i < 4; ++i) {
            int c = tid + i * 256;
            int row = c >> 3, c4 = c & 7;
            float4 v = *(const float4*)(A + (size_t)(m0 + row) * K + k0 + c4 * 4);
            short* dst = &As[row][c4 * 4];
            dst[0] = f2bf(v.x); dst[1] = f2bf(v.y); dst[2] = f2bf(v.z); dst[3] = f2bf(v.w);
        }
#pragma unroll
        for (int i = 0; i < 4; ++i) {
            int c = tid + i * 256;
            int row = c >> 3, c4 = c & 7;
            int gn = n0 + row;
            float4 v = make_float4(0.f, 0.f, 0.f, 0.f);
            if (gn < N) v = *(const float4*)(W + (size_t)gn * K + k0 + c4 * 4);
            short* dst = &Bs[row][c4 * 4];
            dst[0] = f2bf(v.x); dst[1] = f2bf(v.y); dst[2] = f2bf(v.z); dst[3] = f2bf(v.w);
        }
        __syncthreads();

        short8 af[4], bw[4];
#pragma unroll
        for (int i = 0; i < 4; ++i)
            af[i] = *(const short8*)&As[wm + i * 16 + lrow][lq * 8];
#pragma unroll
        for (int j = 0; j < 4; ++j)
            bw[j] = *(const short8*)&Bs[wn + j * 16 + lrow][lq * 8];
#pragma unroll
        for (int i = 0; i < 4; ++i)
#pragma unroll
            for (int j = 0; j < 4; ++j)
                acc[i][j] = __builtin_amdgcn_mfma_f32_16x16x32_bf16(af[i], bw[j], acc[i][j], 0, 0, 0);
        __syncthreads();
    }

    // C/D layout: col = lane&15, row = (lane>>4)*4 + reg  [m89/m91]
    if (mode == 0) {
#pragma unroll
        for (int i = 0; i < 4; ++i)
#pragma unroll
            for (int j = 0; j < 4; ++j)
#pragma unroll
                for (int r = 0; r < 4; ++r) {
                    int m = m0 + wm + i * 16 + lq * 4 + r;
                    int n = n0 + wn + j * 16 + lrow;
                    int b = m >> 10, s = m & 1023;
                    int hh = n >> 6, e = n & 63;
                    out[(((size_t)(b * 8 + hh) * 1024 + s) << 6) + e] =
                        f2bf(acc[i][j][r] * scale);
                }
    } else {
        // mode 2: transpose via LDS, then coalesced 16B stores.
        // waves 0,1 (wn==0) hold all valid n<64; their (i,j,r) cover 128m x 64n.
        if (wn == 0) {
#pragma unroll
            for (int i = 0; i < 4; ++i)
#pragma unroll
                for (int j = 0; j < 4; ++j)
#pragma unroll
                    for (int r = 0; r < 4; ++r) {
                        int ml = wm + i * 16 + lq * 4 + r;     // 0..127 (s-local)
                        int n  = j * 16 + lrow;                // 0..63  (e)
                        ts[n][ml] = f2bf(acc[i][j][r] * scale);
                    }
        }
        __syncthreads();
        int b = m0 >> 10, s0 = m0 & 1023;
#pragma unroll
        for (int i = 0; i < 4; ++i) {
            int c = tid + i * 256;
            int row = c >> 4, c16 = c & 15;    // row=e 0..63, 16B chunk
            *(uint4*)(out + ((size_t)(b * 64 + row) << 10) + s0 + c16 * 8) =
                *(const uint4*)&ts[row][c16 * 8];
        }
    }
}

// ---------------------------------------------------------------------------
// attn_scores: per block = one (b,h) x 64 q-rows.
// exp(scores) unnormalized -> bf16 slab expw[bh][s][1024]; rinv[bh][s]=1/rowsum.
// No max-subtraction needed (|score| small; validated round 1).
// ---------------------------------------------------------------------------
__global__ __launch_bounds__(256) void attn_scores(
    const short* __restrict__ qh, const short* __restrict__ kh,
    short* __restrict__ expw, float* __restrict__ rinv)
{
    __shared__ short qs[64][72];      //  9216 B
    __shared__ short ks[128][72];     // 18432 B
    __shared__ short pa[64][136];     // 17408 B  block's 64x128 exp tile

    const int bh = blockIdx.x;
    const int qbase = blockIdx.y << 6;
    const int tid  = threadIdx.x;
    const int lane = tid & 63, wave = tid >> 6;
    const int lrow = lane & 15, lq = lane >> 4;

    const short* qp = qh + ((size_t)bh << 16);
    const short* kp = kh + ((size_t)bh << 16);
    short* ep = expw + (((size_t)(bh << 10) + qbase) << 10);   // row qbase

#pragma unroll
    for (int i = 0; i < 2; ++i) {
        int c = tid + i * 256;
        int row = c >> 3, c8 = c & 7;
        *(uint4*)&qs[row][c8 * 8] = *(const uint4*)(qp + (size_t)(qbase + row) * 64 + c8 * 8);
    }
    __syncthreads();

    short8 qf[2];
#pragma unroll
    for (int kk = 0; kk < 2; ++kk)
        qf[kk] = *(const short8*)&qs[wave * 16 + lrow][kk * 32 + lq * 8];

    float sume[4] = {0.f, 0.f, 0.f, 0.f};

    for (int kt = 0; kt < 1024; kt += 128) {
        __syncthreads();   // prev iter's pa/ks consumers done
#pragma unroll
        for (int i = 0; i < 4; ++i) {
            int c = tid + i * 256;
            int row = c >> 3, c8 = c & 7;
            *(uint4*)&ks[row][c8 * 8] = *(const uint4*)(kp + (size_t)(kt + row) * 64 + c8 * 8);
        }
        __syncthreads();

#pragma unroll
        for (int j = 0; j < 8; ++j) {
            f32x4 sc = {0.f, 0.f, 0.f, 0.f};
            short8 kb0 = *(const short8*)&ks[j * 16 + lrow][lq * 8];
            short8 kb1 = *(const short8*)&ks[j * 16 + lrow][32 + lq * 8];
            sc = __builtin_amdgcn_mfma_f32_16x16x32_bf16(qf[0], kb0, sc, 0, 0, 0);
            sc = __builtin_amdgcn_mfma_f32_16x16x32_bf16(qf[1], kb1, sc, 0, 0, 0);
#pragma unroll
            for (int r = 0; r < 4; ++r) {
                float e = __expf(sc[r]);
                sume[r] += e;
                pa[wave * 16 + lq * 4 + r][j * 16 + lrow] = f2bf(e);
            }
        }
        __syncthreads();

        // coalesced bf16 store of the 64x128 tile
#pragma unroll
        for (int i = 0; i < 4; ++i) {
            int c = tid + i * 256;
            int row = c >> 4, c16 = c & 15;
            *(uint4*)(ep + ((size_t)row << 10) + kt + c16 * 8) =
                *(const uint4*)&pa[row][c16 * 8];
        }
    }

    // rowsum reduce across the 16 col-lanes (lrow = bits 0..3)
#pragma unroll
    for (int m = 1; m <= 8; m <<= 1)
#pragma unroll
        for (int r = 0; r < 4; ++r) sume[r] += __shfl_xor(sume[r], m, 64);
    if (lrow == 0) {
#pragma unroll
        for (int r = 0; r < 4; ++r)
            rinv[(bh << 10) + qbase + wave * 16 + lq * 4 + r] = 1.0f / sume[r];
    }
}

// ---------------------------------------------------------------------------
// attn_pv: per block = one (b,h) x 64 q-rows.
// Reads exp slab; writes normalized fp32 attn (coalesced) and runs PV MFMA
// with unnormalized weights; scales accumulator by rinv * 1/8 at the end.
// head_bf layout [b*1024+s][h*64+e] bf16 -> final GEMM folds the head mean.
// ---------------------------------------------------------------------------
__global__ __launch_bounds__(256) void attn_pv(
    const short* __restrict__ expw, const float* __restrict__ rinv,
    const short* __restrict__ vt, float* __restrict__ attn_out,
    short* __restrict__ headbf)
{
    __shared__ short es[64][136];     // 17408 B  exp tile
    __shared__ short vts[64][136];    // 17408 B  v^T tile (rows=e, cols=key)
    __shared__ float rs[64];

    const int bh = blockIdx.x;
    const int b = bh >> 3, h = bh & 7;
    const int qbase = blockIdx.y << 6;
    const int tid  = threadIdx.x;
    const int lane = tid & 63, wave = tid >> 6;
    const int lrow = lane & 15, lq = lane >> 4;

    const short* ep = expw + (((size_t)(bh << 10) + qbase) << 10);
    const short* vp = vt + ((size_t)b << 16);

    if (tid < 64) rs[tid] = rinv[(bh << 10) + qbase + tid];

    f32x4 hacc[4] = {};
    const size_t abase0 = (((size_t)(h * 8 + b) * 1024 + qbase) << 10);

    for (int kt = 0; kt < 1024; kt += 128) {
        __syncthreads();
#pragma unroll
        for (int i = 0; i < 4; ++i) {
            int c = tid + i * 256;
            int row = c >> 4, c16 = c & 15;
            *(uint4*)&es[row][c16 * 8]  = *(const uint4*)(ep + ((size_t)row << 10) + kt + c16 * 8);
            *(uint4*)&vts[row][c16 * 8] = *(const uint4*)(vp + ((size_t)row << 10) + kt + c16 * 8);
        }
        __syncthreads();

        // normalize + coalesced fp32 attn store (32 B per thread per iter)
#pragma unroll
        for (int i = 0; i < 4; ++i) {
            int c = tid + i * 256;
            int row = c >> 4, c16 = c & 15;
            float rv = rs[row];
            uint4 pk = *(const uint4*)&es[row][c16 * 8];
            float4 v0, v1;
            v0.x = bfhi2f(pk.x << 16) * rv; v0.y = bfhi2f(pk.x & 0xffff0000u) * rv;
            v0.z = bfhi2f(pk.y << 16) * rv; v0.w = bfhi2f(pk.y & 0xffff0000u) * rv;
            v1.x = bfhi2f(pk.z << 16) * rv; v1.y = bfhi2f(pk.z & 0xffff0000u) * rv;
            v1.z = bfhi2f(pk.w << 16) * rv; v1.w = bfhi2f(pk.w & 0xffff0000u) * rv;
            float* gdst = attn_out + abase0 + ((size_t)row << 10) + kt + c16 * 8;
            *(float4*)gdst       = v0;
            *(float4*)(gdst + 4) = v1;
        }

        // PV: heads[16x64] += exp_tile[16x128] @ v[128x64]
#pragma unroll
        for (int kk = 0; kk < 4; ++kk) {
            short8 af = *(const short8*)&es[wave * 16 + lrow][kk * 32 + lq * 8];
#pragma unroll
            for (int cc = 0; cc < 4; ++cc) {
                short8 bv = *(const short8*)&vts[cc * 16 + lrow][kk * 32 + lq * 8];
                hacc[cc] = __builtin_amdgcn_mfma_f32_16x16x32_bf16(af, bv, hacc[cc], 0, 0, 0);
            }
        }
    }

    // epilogue: scale by rinv * 1/8, store bf16 head slice (this head's cols)
#pragma unroll
    for (int cc = 0; cc < 4; ++cc)
#pragma unroll
        for (int r = 0; r < 4; ++r) {
            int srow = wave * 16 + lq * 4 + r;
            float v = hacc[cc][r] * rs[srow] * 0.125f;
            headbf[(size_t)(b * 1024 + qbase + srow) * 512 + h * 64 + cc * 16 + lrow] = f2bf(v);
        }
}

// ---------------------------------------------------------------------------
// gemm_out: out[m][n] = sum_{k<512} head_bf[m][k] * Wo[n][k&63]
// (head mean already folded by the 0.125 factor in attn_pv)
// ---------------------------------------------------------------------------
__global__ __launch_bounds__(256) void gemm_out(
    const short* __restrict__ A, const float* __restrict__ Wo,
    float* __restrict__ out)
{
    __shared__ short As[128][40];
    __shared__ short Bs[128][40];

    const int tid  = threadIdx.x;
    const int m0   = blockIdx.x * 128;
    const int n0   = blockIdx.y * 128;
    const int lane = tid & 63, wave = tid >> 6;
    const int wm   = (wave & 1) * 64, wn = (wave >> 1) * 64;
    const int lrow = lane & 15, lq = lane >> 4;

    f32x4 acc[4][4] = {};

    for (int k0 = 0; k0 < 512; k0 += 32) {
        // A: bf16 direct staging (128 x 32 shorts)
#pragma unroll
        for (int i = 0; i < 2; ++i) {
            int c = tid + i * 256;
            int row = c >> 2, c8 = c & 3;
            *(uint4*)&As[row][c8 * 8] = *(const uint4*)(A + (size_t)(m0 + row) * 512 + k0 + c8 * 8);
        }
        // W: Wo replicated across heads: Wrep[n][k] = Wo[n][k&63]
#pragma unroll
        for (int i = 0; i < 4; ++i) {
            int c = tid + i * 256;
            int row = c >> 3, c4 = c & 7;
            float4 v = *(const float4*)(Wo + (size_t)(n0 + row) * 64 + (k0 & 63) + c4 * 4);
            short* dst = &Bs[row][c4 * 4];
            dst[0] = f2bf(v.x); dst[1] = f2bf(v.y); dst[2] = f2bf(v.z); dst[3] = f2bf(v.w);
        }
        __syncthreads();

        short8 af[4], bw[4];
#pragma unroll
        for (int i = 0; i < 4; ++i)
            af[i] = *(const short8*)&As[wm + i * 16 + lrow][lq * 8];
#pragma unroll
        for (int j = 0; j < 4; ++j)
            bw[j] = *(const short8*)&Bs[wn + j * 16 + lrow][lq * 8];
#pragma unroll
        for (int i = 0; i < 4; ++i)
#pragma unroll
            for (int j = 0; j < 4; ++j)
                acc[i][j] = __builtin_amdgcn_mfma_f32_16x16x32_bf16(af[i], bw[j], acc[i][j], 0, 0, 0);
        __syncthreads();
    }

#pragma unroll
    for (int i = 0; i < 4; ++i)
#pragma unroll
        for (int j = 0; j < 4; ++j)
#pragma unroll
            for (int r = 0; r < 4; ++r) {
                int m = m0 + wm + i * 16 + lq * 4 + r;
                int n = n0 + wn + j * 16 + lrow;
                out[(size_t)m * 512 + n] = acc[i][j][r];
            }
}

// ---------------------------------------------------------------------------
extern "C" void kernel_launch(void* const* d_in, const int* in_sizes, int n_in,
                              void* d_out, int out_size, void* d_ws, size_t ws_size,
                              hipStream_t stream)
{
    (void)in_sizes; (void)n_in; (void)out_size; (void)ws_size;

    const float* q  = (const float*)d_in[0];
    const float* k  = (const float*)d_in[1];
    const float* v  = (const float*)d_in[2];
    const float* Wq = (const float*)d_in[3];
    const float* Wk = (const float*)d_in[4];
    const float* Wv = (const float*)d_in[5];
    const float* Wo = (const float*)d_in[6];

    float* out  = (float*)d_out;
    float* attn = out + (size_t)8 * 1024 * 512;

    char* ws = (char*)d_ws;
    short* qh     = (short*)(ws);                        //  8 MB  [b][h][s][64]
    short* kh     = (short*)(ws + ((size_t)8  << 20));   //  8 MB
    short* vt     = (short*)(ws + ((size_t)16 << 20));   //  1 MB  [b][64][1024]
    short* headbf = (short*)(ws + ((size_t)17 << 20));   //  8 MB  [b*1024+s][512]
    float* rinvb  = (float*)(ws + ((size_t)25 << 20));   // 256 KB [bh][1024]
    short* expw   = (short*)(ws + ((size_t)26 << 20));   // 128 MB [bh][1024][1024]

    gemm_proj<<<dim3(64, 4), 256, 0, stream>>>(q, Wq, qh, 512, 512, 0.125f, 0);
    gemm_proj<<<dim3(64, 4), 256, 0, stream>>>(k, Wk, kh, 512, 512, 1.0f, 0);
    gemm_proj<<<dim3(64, 1), 256, 0, stream>>>(v, Wv, vt, 64, 512, 1.0f, 2);

    attn_scores<<<dim3(64, 16), 256, 0, stream>>>(qh, kh, expw, rinvb);
    attn_pv<<<dim3(64, 16), 256, 0, stream>>>(expw, rinvb, vt, attn, headbf);

    gemm_out<<<dim3(64, 4), 256, 0, stream>>>(headbf, Wo, out);
}